// Round 6
// baseline (130.996 us; speedup 1.0000x reference)
//
#include <hip/hip_runtime.h>
#include <hip/hip_bf16.h>

typedef short bf16x8 __attribute__((ext_vector_type(8)));
typedef float f32x4 __attribute__((ext_vector_type(4)));
typedef unsigned short u16;
typedef long f8x8;
typedef unsigned char u8;

#define NB2 (-0.35f * 1.44269504088896340736f)
#define MFP8(a,b,c) __builtin_amdgcn_mfma_f32_16x16x32_fp8_fp8(a, b, c, 0, 0, 0)
#define MFBF(a,b,c) __builtin_amdgcn_mfma_f32_16x16x32_bf16(a, b, c, 0, 0, 0)

__device__ __forceinline__ u16 f2bf(float f) {
  union { float f; unsigned int u; } v; v.f = f;
  unsigned int x = v.u;
  return (u16)((x + 0x7FFFu + ((x >> 16) & 1u)) >> 16);
}

__device__ __forceinline__ u8 f2e4m3(float f) {
  unsigned int u = __float_as_uint(f);
  u8 s = (u8)((u >> 24) & 0x80u);
  float a = fabsf(f);
  if (a >= 448.f) return s | 0x7E;
  if (a < 0.015625f) return s | (u8)(int)rintf(a * 512.f);
  unsigned int m = u & 0x7fffffffu;
  unsigned int r = m + 0x7FFFFu + ((m >> 20) & 1u);
  return s | (u8)((((r >> 23) - 120u) << 3) | ((r >> 20) & 7u));
}

__device__ __forceinline__ unsigned int pk4(float a, float b, float c, float d) {
#if __has_builtin(__builtin_amdgcn_cvt_pk_fp8_f32)
  int v = __builtin_amdgcn_cvt_pk_fp8_f32(a, b, 0, false);
  v = __builtin_amdgcn_cvt_pk_fp8_f32(c, d, v, true);
  return (unsigned int)v;
#else
  return (unsigned int)f2e4m3(a) | ((unsigned int)f2e4m3(b) << 8)
       | ((unsigned int)f2e4m3(c) << 16) | ((unsigned int)f2e4m3(d) << 24);
#endif
}

#define GLOAD_LDS(g, l) __builtin_amdgcn_global_load_lds( \
    (const __attribute__((address_space(1))) unsigned int*)(g), \
    (__attribute__((address_space(3))) unsigned int*)(l), 16, 0, 0)

// ---------- prep: fp32 rows -> fp8 e4m3 rows + row sum-of-squares ----------
__global__ __launch_bounds__(512)
void prep_f8(const float* __restrict__ src, u8* __restrict__ dst,
             float* __restrict__ sq) {
  const int row = blockIdx.x * 8 + (threadIdx.x >> 6);
  const int lane = threadIdx.x & 63;
  const float4* p = (const float4*)(src + (size_t)row * 512) + lane * 2;
  float4 a = p[0], b = p[1];
  float ss = a.x*a.x + a.y*a.y + a.z*a.z + a.w*a.w
           + b.x*b.x + b.y*b.y + b.z*b.z + b.w*b.w;
  uint2 o;
  o.x = pk4(a.x, a.y, a.z, a.w);
  o.y = pk4(b.x, b.y, b.z, b.w);
  ((uint2*)(dst + (size_t)row * 512))[lane] = o;
  ss += __shfl_xor(ss, 1);  ss += __shfl_xor(ss, 2);
  ss += __shfl_xor(ss, 4);  ss += __shfl_xor(ss, 8);
  ss += __shfl_xor(ss, 16); ss += __shfl_xor(ss, 32);
  if (lane == 0) sq[row] = ss;
}

// ---------- prep: W [4096][128] f32 -> Wt [128][4096] bf16 ----------
__global__ __launch_bounds__(256)
void prep_w(const float* __restrict__ W, u16* __restrict__ wt) {
  __shared__ u16 t_[128 * 66];
  const int c0 = blockIdx.x * 64;
  const int t = threadIdx.x;
#pragma unroll
  for (int it = 0; it < 32; ++it) {
    int idx = it * 256 + t;
    int cl = idx >> 7;
    int o  = idx & 127;
    t_[o * 66 + cl] = f2bf(W[(size_t)(c0 + cl) * 128 + o]);
  }
  __syncthreads();
#pragma unroll
  for (int it = 0; it < 8; ++it) {
    int idx = it * 256 + t;
    int o  = idx >> 4;
    int cq = idx & 15;
    u16 h0 = t_[o * 66 + cq * 4 + 0], h1 = t_[o * 66 + cq * 4 + 1];
    u16 h2 = t_[o * 66 + cq * 4 + 2], h3 = t_[o * 66 + cq * 4 + 3];
    u16* d = &wt[(size_t)o * 4096 + c0 + cq * 4];
    d[0] = h0; d[1] = h1; d[2] = h2; d[3] = h3;
  }
}

// ---------- init: out = bias ----------
__global__ __launch_bounds__(256)
void init_out(const float* __restrict__ bias, float* __restrict__ out) {
  const int i4 = blockIdx.x * 256 + threadIdx.x;
  float4 b = ((const float4*)bias)[i4 & 31];
  ((float4*)out)[i4] = b;
}

// ---------- main: 256 blocks = 64 row-tiles(256) x 4 center-quarters(1024) ----------
__global__ __launch_bounds__(512, 2)
void rbf_main(const u8* __restrict__ xq8, const u8* __restrict__ cq8,
              const u16* __restrict__ wtg, const float* __restrict__ csq_g,
              const float* __restrict__ xsq_g, float* __restrict__ out)
{
  __shared__ u8 cs[4][8192];     // 4 pair-slots: [64c][128B k], src-XOR swizzled; 32 KB
  __shared__ u16 wt[2][8192];    // W chunk [128o][64c] dbuf, 32 KB
  __shared__ u16 pl[16384];      // P tile [256m][64c], 32 KB
  __shared__ float csq_l[1024];  // quarter csq, 4 KB
  __shared__ float xsq_l[256];   // 1 KB

  const int tid = threadIdx.x;
  const int lane = tid & 63;
  const int mw = tid >> 6;       // wave 0..7 -> rows mw*32..+32
  const int l15 = lane & 15;
  const int lg = lane >> 4;
  const int bid = blockIdx.x;
  const int chq = bid & 3;
  const size_t r0 = (size_t)(bid >> 2) * 256;
  const size_t cb8 = (size_t)chq * (1024 * 512);
  const int chW = chq * 1024;

  // staging maps
  const int pc = tid >> 3, pu = tid & 7;                       // pair-stage: row, 16B-unit
  const int pair_src = pc * 512 + ((pu ^ (pc & 7)) * 16);
  u8* const cs_dst = &cs[0][0] + tid * 16;
  const int scr = tid >> 3, sgk = tid & 7;                     // W stage (R5 layout)
  const int wt_src = scr * 4096 + ((sgk ^ (scr & 7)) * 8);
  u16* const wt_dst = &wt[0][0] + tid * 8;

#define S_P(cc, p, slot) \
  GLOAD_LDS(cq8 + cb8 + (cc) * 32768 + (p) * 128 + pair_src, cs_dst + (slot) * 8192)
#define S_W(cc, slot) do { \
  GLOAD_LDS(wtg + chW + (cc) * 64 + wt_src,          wt_dst + (slot) * 8192); \
  GLOAD_LDS(wtg + 262144 + chW + (cc) * 64 + wt_src, wt_dst + (slot) * 8192 + 4096); \
} while (0)

  // prologue staging: xsq, csq, pair0(0), pair1(0), W(0)
  if (tid < 64)  GLOAD_LDS(xsq_g + r0 + tid * 4, xsq_l + tid * 4);
  if (tid < 256) GLOAD_LDS(csq_g + chW + tid * 4, csq_l + tid * 4);
  S_P(0, 0, 0);
  S_P(0, 1, 1);
  S_W(0, 0);

  // ---- x fragments (fp8) -> registers ----
  f8x8 xf[2][16];
#pragma unroll
  for (int rh = 0; rh < 2; ++rh) {
    const u8* xr = xq8 + (r0 + mw * 32 + rh * 16 + l15) * 512 + lg * 8;
#pragma unroll
    for (int ks = 0; ks < 16; ++ks)
      xf[rh][ks] = *(const f8x8*)(xr + ks * 32);
  }

  asm volatile("s_waitcnt vmcnt(4)" ::: "memory");
  __builtin_amdgcn_s_barrier();

  float xq[2][4], cq[4];
#pragma unroll
  for (int rh = 0; rh < 2; ++rh)
#pragma unroll
    for (int r = 0; r < 4; ++r) xq[rh][r] = xsq_l[mw * 32 + rh * 16 + lg * 4 + r];
#pragma unroll
  for (int ct = 0; ct < 4; ++ct) cq[ct] = csq_l[ct * 16 + l15];

  // B-frag LDS byte offsets (swizzled): unit = sub*4+ksl*2+(lg>>1)
#define BOFF(sub, ksl, ct) \
  (((ct) * 16 + l15) * 128 + \
   ((((sub) * 4 + (ksl) * 2 + (lg >> 1)) ^ (l15 & 7)) << 4) + (lg & 1) * 8)

  // GEMM2 offsets (elements)
  const int wsw0 = (lg * 8) ^ ((l15 & 7) << 3);
  const int wsw1 = (32 + lg * 8) ^ ((l15 & 7) << 3);
  const int pabase = mw * 2048 + l15 * 64;
  const int wbase = l15 * 64;

  const f32x4 z4 = {0.f, 0.f, 0.f, 0.f};
  f32x4 sacc[2][4] = {{z4, z4, z4, z4}, {z4, z4, z4, z4}};
  f32x4 oa[2][8] = {{z4, z4, z4, z4, z4, z4, z4, z4},
                    {z4, z4, z4, z4, z4, z4, z4, z4}};

#define QUAD(rh, kidx, B0, B1, B2, B3) \
  sacc[rh][0] = MFP8(xf[rh][kidx], B0, sacc[rh][0]); \
  sacc[rh][1] = MFP8(xf[rh][kidx], B1, sacc[rh][1]); \
  sacc[rh][2] = MFP8(xf[rh][kidx], B2, sacc[rh][2]); \
  sacc[rh][3] = MFP8(xf[rh][kidx], B3, sacc[rh][3]);

#define PHASE(p, VM, STMTS) do { \
    asm volatile("s_waitcnt vmcnt(" #VM ")" ::: "memory"); \
    __builtin_amdgcn_s_barrier(); \
    __builtin_amdgcn_sched_barrier(0); \
    const u8* cb_ = &cs[p][0]; \
    f8x8 b00 = *(const f8x8*)(cb_ + BOFF(0, 0, 0)); \
    f8x8 b01 = *(const f8x8*)(cb_ + BOFF(0, 0, 1)); \
    f8x8 b02 = *(const f8x8*)(cb_ + BOFF(0, 0, 2)); \
    f8x8 b03 = *(const f8x8*)(cb_ + BOFF(0, 0, 3)); \
    f8x8 b10 = *(const f8x8*)(cb_ + BOFF(0, 1, 0)); \
    f8x8 b11 = *(const f8x8*)(cb_ + BOFF(0, 1, 1)); \
    f8x8 b12 = *(const f8x8*)(cb_ + BOFF(0, 1, 2)); \
    f8x8 b13 = *(const f8x8*)(cb_ + BOFF(0, 1, 3)); \
    STMTS; \
    __builtin_amdgcn_s_setprio(1); \
    QUAD(0, 4 * (p) + 0, b00, b01, b02, b03); \
    QUAD(1, 4 * (p) + 0, b00, b01, b02, b03); \
    QUAD(0, 4 * (p) + 1, b10, b11, b12, b13); \
    QUAD(1, 4 * (p) + 1, b10, b11, b12, b13); \
    __builtin_amdgcn_s_setprio(0); \
    f8x8 c00 = *(const f8x8*)(cb_ + BOFF(1, 0, 0)); \
    f8x8 c01 = *(const f8x8*)(cb_ + BOFF(1, 0, 1)); \
    f8x8 c02 = *(const f8x8*)(cb_ + BOFF(1, 0, 2)); \
    f8x8 c03 = *(const f8x8*)(cb_ + BOFF(1, 0, 3)); \
    f8x8 c10 = *(const f8x8*)(cb_ + BOFF(1, 1, 0)); \
    f8x8 c11 = *(const f8x8*)(cb_ + BOFF(1, 1, 1)); \
    f8x8 c12 = *(const f8x8*)(cb_ + BOFF(1, 1, 2)); \
    f8x8 c13 = *(const f8x8*)(cb_ + BOFF(1, 1, 3)); \
    __builtin_amdgcn_s_setprio(1); \
    QUAD(0, 4 * (p) + 2, c00, c01, c02, c03); \
    QUAD(1, 4 * (p) + 2, c00, c01, c02, c03); \
    QUAD(0, 4 * (p) + 3, c10, c11, c12, c13); \
    QUAD(1, 4 * (p) + 3, c10, c11, c12, c13); \
    __builtin_amdgcn_s_setprio(0); \
  } while (0)

#define G2HALF(WSW, PW) do { \
    bf16x8 paA = *(const bf16x8*)(pl + pabase + (WSW)); \
    bf16x8 paB = *(const bf16x8*)(pl + pabase + 1024 + (WSW)); \
    const u16* wb_ = (PW) + wbase + (WSW); \
    bf16x8 w0 = *(const bf16x8*)(wb_); \
    bf16x8 w1 = *(const bf16x8*)(wb_ + 1024); \
    bf16x8 w2 = *(const bf16x8*)(wb_ + 2048); \
    bf16x8 w3 = *(const bf16x8*)(wb_ + 3072); \
    bf16x8 w4 = *(const bf16x8*)(wb_ + 4096); \
    bf16x8 w5 = *(const bf16x8*)(wb_ + 5120); \
    bf16x8 w6 = *(const bf16x8*)(wb_ + 6144); \
    bf16x8 w7 = *(const bf16x8*)(wb_ + 7168); \
    __builtin_amdgcn_s_setprio(1); \
    oa[0][0] = MFBF(paA, w0, oa[0][0]); oa[0][1] = MFBF(paA, w1, oa[0][1]); \
    oa[0][2] = MFBF(paA, w2, oa[0][2]); oa[0][3] = MFBF(paA, w3, oa[0][3]); \
    oa[0][4] = MFBF(paA, w4, oa[0][4]); oa[0][5] = MFBF(paA, w5, oa[0][5]); \
    oa[0][6] = MFBF(paA, w6, oa[0][6]); oa[0][7] = MFBF(paA, w7, oa[0][7]); \
    oa[1][0] = MFBF(paB, w0, oa[1][0]); oa[1][1] = MFBF(paB, w1, oa[1][1]); \
    oa[1][2] = MFBF(paB, w2, oa[1][2]); oa[1][3] = MFBF(paB, w3, oa[1][3]); \
    oa[1][4] = MFBF(paB, w4, oa[1][4]); oa[1][5] = MFBF(paB, w5, oa[1][5]); \
    oa[1][6] = MFBF(paB, w6, oa[1][6]); oa[1][7] = MFBF(paB, w7, oa[1][7]); \
    __builtin_amdgcn_s_setprio(0); \
  } while (0)

#define TAIL(WS, NC) do { \
    _Pragma("unroll") \
    for (int rh = 0; rh < 2; ++rh) { \
      _Pragma("unroll") \
      for (int ct = 0; ct < 4; ++ct) { \
        _Pragma("unroll") \
        for (int r = 0; r < 4; ++r) { \
          const int m_ = mw * 32 + rh * 16 + lg * 4 + r; \
          float v_ = __builtin_amdgcn_exp2f(NB2 * (xq[rh][r] + cq[ct] - 2.f * sacc[rh][ct][r])); \
          pl[m_ * 64 + ((ct * 16 + l15) ^ ((m_ & 7) << 3))] = f2bf(v_); \
        } \
        sacc[rh][ct] = z4; \
      } \
    } \
    asm volatile("s_waitcnt lgkmcnt(0)" ::: "memory"); \
    __builtin_amdgcn_s_barrier(); \
    __builtin_amdgcn_sched_barrier(0); \
    const u16* pw_ = &wt[WS][0]; \
    G2HALF(wsw0, pw_); \
    G2HALF(wsw1, pw_); \
    _Pragma("unroll") \
    for (int ct = 0; ct < 4; ++ct) cq[ct] = csq_l[(NC) * 64 + ct * 16 + l15]; \
  } while (0)

  // ---- chunk 0 ----
  PHASE(0, 3, S_P(0, 2, 2));
  PHASE(1, 3, S_P(0, 3, 3); S_W(1, 1));
  PHASE(2, 3, S_P(1, 0, 0));
  PHASE(3, 3, S_P(1, 1, 1));
  TAIL(0, 1);

  // ---- steady chunks ----
  for (int cc = 1; cc < 15; ++cc) {
    PHASE(0, 1, S_P(cc, 2, 2));
    PHASE(1, 1, S_P(cc, 3, 3); S_W(cc + 1, (cc + 1) & 1));
    PHASE(2, 3, S_P(cc + 1, 0, 0));
    PHASE(3, 3, S_P(cc + 1, 1, 1));
    TAIL(cc & 1, cc + 1);
  }

  // ---- chunk 15 (drain) ----
  PHASE(0, 1, (void)0);
  PHASE(1, 0, (void)0);
  PHASE(2, 0, (void)0);
  PHASE(3, 0, (void)0);
  TAIL(1, 15);

  // ---- epilogue: out += partial (bias added by init_out) ----
#pragma unroll
  for (int rh = 0; rh < 2; ++rh)
#pragma unroll
    for (int ot = 0; ot < 8; ++ot) {
      const int o = ot * 16 + l15;
#pragma unroll
      for (int r = 0; r < 4; ++r) {
        const int m = mw * 32 + rh * 16 + lg * 4 + r;
        atomicAdd(&out[(r0 + m) * 128 + o], oa[rh][ot][r]);
      }
    }
#undef PHASE
#undef TAIL
#undef QUAD
#undef G2HALF
#undef BOFF
#undef S_P
#undef S_W
}

extern "C" void kernel_launch(void* const* d_in, const int* in_sizes, int n_in,
                              void* d_out, int out_size, void* d_ws, size_t ws_size,
                              hipStream_t stream) {
  (void)in_sizes; (void)n_in; (void)out_size; (void)ws_size;
  const float* x   = (const float*)d_in[0];
  const float* cen = (const float*)d_in[1];
  const float* W   = (const float*)d_in[2];
  const float* b   = (const float*)d_in[3];
  u8* xq8 = (u8*)d_ws;                          // 16384*512 = 8 MB
  u8* cq8 = xq8 + (size_t)16384 * 512;          // 4096*512  = 2 MB
  u16* wtg = (u16*)(cq8 + (size_t)4096 * 512);  // 128*4096 bf16 = 1 MB
  float* csq = (float*)(wtg + 128 * 4096);      // 16 KB
  float* xsq = csq + 4096;                      // 64 KB
  prep_f8<<<2048, 512, 0, stream>>>(x, xq8, xsq);
  prep_f8<<<512, 512, 0, stream>>>(cen, cq8, csq);
  prep_w<<<64, 256, 0, stream>>>(W, wtg);
  init_out<<<2048, 256, 0, stream>>>(b, (float*)d_out);
  rbf_main<<<256, 512, 0, stream>>>(xq8, cq8, wtg, csq, xsq, (float*)d_out);
}

// Round 7
// 111.953 us; speedup vs baseline: 1.1701x; 1.1701x over previous
//
#include <hip/hip_runtime.h>
#include <hip/hip_bf16.h>

typedef short bf16x8 __attribute__((ext_vector_type(8)));
typedef float f32x4 __attribute__((ext_vector_type(4)));
typedef long l64x2 __attribute__((ext_vector_type(2)));
typedef unsigned short u16;
typedef unsigned char u8;

#define NB2 (-0.35f * 1.44269504088896340736f)
#define MFP8(a,b,c) __builtin_amdgcn_mfma_f32_16x16x32_fp8_fp8(a, b, c, 0, 0, 0)
#define MFBF(a,b,c) __builtin_amdgcn_mfma_f32_16x16x32_bf16(a, b, c, 0, 0, 0)

__device__ __forceinline__ u16 f2bf(float f) {
  union { float f; unsigned int u; } v; v.f = f;
  unsigned int x = v.u;
  return (u16)((x + 0x7FFFu + ((x >> 16) & 1u)) >> 16);
}

__device__ __forceinline__ u8 f2e4m3(float f) {
  unsigned int u = __float_as_uint(f);
  u8 s = (u8)((u >> 24) & 0x80u);
  float a = fabsf(f);
  if (a >= 448.f) return s | 0x7E;
  if (a < 0.015625f) return s | (u8)(int)rintf(a * 512.f);
  unsigned int m = u & 0x7fffffffu;
  unsigned int r = m + 0x7FFFFu + ((m >> 20) & 1u);
  return s | (u8)((((r >> 23) - 120u) << 3) | ((r >> 20) & 7u));
}

__device__ __forceinline__ unsigned int pk4(float a, float b, float c, float d) {
#if __has_builtin(__builtin_amdgcn_cvt_pk_fp8_f32)
  int v = __builtin_amdgcn_cvt_pk_fp8_f32(a, b, 0, false);
  v = __builtin_amdgcn_cvt_pk_fp8_f32(c, d, v, true);
  return (unsigned int)v;
#else
  return (unsigned int)f2e4m3(a) | ((unsigned int)f2e4m3(b) << 8)
       | ((unsigned int)f2e4m3(c) << 16) | ((unsigned int)f2e4m3(d) << 24);
#endif
}

#define GLOAD_LDS(g, l) __builtin_amdgcn_global_load_lds( \
    (const __attribute__((address_space(1))) unsigned int*)(g), \
    (__attribute__((address_space(3))) unsigned int*)(l), 16, 0, 0)

// ---------- prep: x fp32 rows -> fp8 rows + row sum-of-squares ----------
__global__ __launch_bounds__(512)
void prep_x8(const float* __restrict__ src, u8* __restrict__ dst,
             float* __restrict__ sq) {
  const int row = blockIdx.x * 8 + (threadIdx.x >> 6);
  const int lane = threadIdx.x & 63;
  const float4* p = (const float4*)(src + (size_t)row * 512) + lane * 2;
  float4 a = p[0], b = p[1];
  float ss = a.x*a.x + a.y*a.y + a.z*a.z + a.w*a.w
           + b.x*b.x + b.y*b.y + b.z*b.z + b.w*b.w;
  uint2 o;
  o.x = pk4(a.x, a.y, a.z, a.w);
  o.y = pk4(b.x, b.y, b.z, b.w);
  ((uint2*)(dst + (size_t)row * 512))[lane] = o;
  ss += __shfl_xor(ss, 1);  ss += __shfl_xor(ss, 2);
  ss += __shfl_xor(ss, 4);  ss += __shfl_xor(ss, 8);
  ss += __shfl_xor(ss, 16); ss += __shfl_xor(ss, 32);
  if (lane == 0) sq[row] = ss;
}

// ---------- prep: centers -> fp8 frag-stream (role-major k + XOR swizzle) + csq ----------
// layout: cfr[(c>>6)*32768 + sl*8192 + (c&63)*128 + u*16 + (s&1)*8]
//   logical granule g = lg*2 + (s>>1); stored unit u = g ^ (c&7); k = (sl*4+s)*32 + lg*8
__global__ __launch_bounds__(256)
void prep_cen(const float* __restrict__ cen, u8* __restrict__ cfr,
              float* __restrict__ csq) {
  const int t = threadIdx.x;
  const int c = blockIdx.x * 4 + (t >> 6);
  const int i6 = t & 63;                  // sl*16 + s*4 + lg
  const int sl = i6 >> 4, s = (i6 >> 2) & 3, lg = i6 & 3;
  const float* p = cen + (size_t)c * 512 + i6 * 8;
  float4 a = *(const float4*)p, b = *(const float4*)(p + 4);
  float ss = a.x*a.x + a.y*a.y + a.z*a.z + a.w*a.w
           + b.x*b.x + b.y*b.y + b.z*b.z + b.w*b.w;
  uint2 o;
  o.x = pk4(a.x, a.y, a.z, a.w);
  o.y = pk4(b.x, b.y, b.z, b.w);
  const int u = (lg * 2 + (s >> 1)) ^ (c & 7);
  *(uint2*)(cfr + (size_t)(c >> 6) * 32768 + sl * 8192 + (c & 63) * 128
            + u * 16 + (s & 1) * 8) = o;
  ss += __shfl_xor(ss, 1);  ss += __shfl_xor(ss, 2);
  ss += __shfl_xor(ss, 4);  ss += __shfl_xor(ss, 8);
  ss += __shfl_xor(ss, 16); ss += __shfl_xor(ss, 32);
  if (i6 == 0) csq[c] = ss;
}

// ---------- prep: W [4096][128] f32 -> Wt [128][4096] bf16 ----------
__global__ __launch_bounds__(256)
void prep_w(const float* __restrict__ W, u16* __restrict__ wt) {
  __shared__ u16 t_[128 * 66];
  const int c0 = blockIdx.x * 64;
  const int t = threadIdx.x;
#pragma unroll
  for (int it = 0; it < 32; ++it) {
    int idx = it * 256 + t;
    int cl = idx >> 7;
    int o  = idx & 127;
    t_[o * 66 + cl] = f2bf(W[(size_t)(c0 + cl) * 128 + o]);
  }
  __syncthreads();
#pragma unroll
  for (int it = 0; it < 8; ++it) {
    int idx = it * 256 + t;
    int o  = idx >> 4;
    int cq = idx & 15;
    u16 h0 = t_[o * 66 + cq * 4 + 0], h1 = t_[o * 66 + cq * 4 + 1];
    u16 h2 = t_[o * 66 + cq * 4 + 2], h3 = t_[o * 66 + cq * 4 + 3];
    u16* d = &wt[(size_t)o * 4096 + c0 + cq * 4];
    d[0] = h0; d[1] = h1; d[2] = h2; d[3] = h3;
  }
}

// ---------- init: out = bias ----------
__global__ __launch_bounds__(256)
void init_out(const float* __restrict__ bias, float* __restrict__ out) {
  const int i4 = blockIdx.x * 256 + threadIdx.x;
  float4 b = ((const float4*)bias)[i4 & 31];
  ((float4*)out)[i4] = b;
}

// ---------- main: 256 blocks = 64 row-tiles(256) x 4 center-quarters(1024) ----------
// One vmcnt(0)+barrier per chunk; intra-chunk fully barrier-free (P is wave-private).
__global__ __launch_bounds__(512)
void rbf_main(const u8* __restrict__ xq8, const u8* __restrict__ cfr,
              const u16* __restrict__ wtg, const float* __restrict__ csq_g,
              const float* __restrict__ xsq_g, float* __restrict__ out)
{
  __shared__ __align__(16) u8  cs[2][32768];   // chunk dbuf (4 slots x [64c][128B]), 64 KB
  __shared__ __align__(16) u16 wt[2][8192];    // W chunk [128o][64c] dbuf, 32 KB
  __shared__ __align__(16) u16 pl[16384];      // P tile [256m][64c], 32 KB (wave-private rows)
  __shared__ __align__(16) float csq_l[1024];
  __shared__ __align__(16) float xsq_l[256];

  const int tid = threadIdx.x;
  const int lane = tid & 63;
  const int mw = tid >> 6;
  const int l15 = lane & 15;
  const int lg = lane >> 4;
  const int bid = blockIdx.x;
  const int chq = bid & 3;
  const size_t r0 = (size_t)(bid >> 2) * 256;
  const int chW = chq * 1024;

  // W staging (pre-swizzled global source, linear LDS dest)
  const int scr = tid >> 3, sgk = tid & 7;
  const int wt_src = scr * 4096 + ((sgk ^ (scr & 7)) * 8);
  u16* const wt_dst = &wt[0][0] + tid * 8;

#define S_CS(cc) do { \
    const u8* sG_ = cfr + ((size_t)(chq * 16 + (cc)) << 15) + tid * 16; \
    u8* sL_ = &cs[(cc) & 1][0] + tid * 16; \
    GLOAD_LDS(sG_,          sL_); \
    GLOAD_LDS(sG_ + 8192,   sL_ + 8192); \
    GLOAD_LDS(sG_ + 16384,  sL_ + 16384); \
    GLOAD_LDS(sG_ + 24576,  sL_ + 24576); \
  } while (0)

#define S_W(cc) do { \
    const u16* wg_ = wtg + chW + (cc) * 64 + wt_src; \
    u16* wl_ = wt_dst + ((cc) & 1) * 8192; \
    GLOAD_LDS(wg_,          wl_); \
    GLOAD_LDS(wg_ + 262144, wl_ + 4096); \
  } while (0)

  // prologue staging
  if (tid < 64)  GLOAD_LDS(xsq_g + r0 + tid * 4, xsq_l + tid * 4);
  if (tid < 256) GLOAD_LDS(csq_g + chW + tid * 4, csq_l + tid * 4);
  S_CS(0);
  S_W(0);

  // x fragments (fp8) -> registers
  long xf[2][16];
#pragma unroll
  for (int rh = 0; rh < 2; ++rh) {
    const u8* xr = xq8 + (r0 + mw * 32 + rh * 16 + l15) * 512 + lg * 8;
#pragma unroll
    for (int ks = 0; ks < 16; ++ks)
      xf[rh][ks] = *(const long*)(xr + ks * 32);
  }

  asm volatile("s_waitcnt vmcnt(0)" ::: "memory");
  __builtin_amdgcn_s_barrier();
  __builtin_amdgcn_sched_barrier(0);

  float xq[2][4], cq[4];
#pragma unroll
  for (int rh = 0; rh < 2; ++rh)
#pragma unroll
    for (int r = 0; r < 4; ++r) xq[rh][r] = xsq_l[mw * 32 + rh * 16 + lg * 4 + r];
#pragma unroll
  for (int ct = 0; ct < 4; ++ct) cq[ct] = csq_l[ct * 16 + l15];

  // LDS byte-offset bases
  const int sw7 = l15 & 7;
  const int cbase  = l15 * 128 + (((lg * 2) ^ sw7) << 4);          // B-frags (fp8, b128)
  const int pabase = (mw * 32 + l15) * 128 + ((lg ^ sw7) << 4);    // P A-frags (bf16)
  const int wobase = l15 * 128 + ((lg ^ sw7) << 4);                // W B-frags (bf16)

  const f32x4 z4 = {0.f, 0.f, 0.f, 0.f};
  f32x4 sacc[2][4] = {{z4, z4, z4, z4}, {z4, z4, z4, z4}};
  f32x4 oa[2][8] = {{z4, z4, z4, z4, z4, z4, z4, z4},
                    {z4, z4, z4, z4, z4, z4, z4, z4}};

#define QUAD(rh, kidx, q0, q1, q2, q3) \
    sacc[rh][0] = MFP8(xf[rh][kidx], q0, sacc[rh][0]); \
    sacc[rh][1] = MFP8(xf[rh][kidx], q1, sacc[rh][1]); \
    sacc[rh][2] = MFP8(xf[rh][kidx], q2, sacc[rh][2]); \
    sacc[rh][3] = MFP8(xf[rh][kidx], q3, sacc[rh][3]);

#define PHASE(CSH, p) do { \
    const u8* pb_ = (CSH) + (p) * 8192; \
    l64x2 A0 = *(const l64x2*)(pb_ + cbase); \
    l64x2 A1 = *(const l64x2*)(pb_ + cbase + 2048); \
    l64x2 A2 = *(const l64x2*)(pb_ + cbase + 4096); \
    l64x2 A3 = *(const l64x2*)(pb_ + cbase + 6144); \
    __builtin_amdgcn_s_setprio(1); \
    QUAD(0, 4*(p)+0, A0[0], A1[0], A2[0], A3[0]) \
    QUAD(1, 4*(p)+0, A0[0], A1[0], A2[0], A3[0]) \
    QUAD(0, 4*(p)+1, A0[1], A1[1], A2[1], A3[1]) \
    QUAD(1, 4*(p)+1, A0[1], A1[1], A2[1], A3[1]) \
    __builtin_amdgcn_s_setprio(0); \
    l64x2 C0 = *(const l64x2*)(pb_ + (cbase ^ 16)); \
    l64x2 C1 = *(const l64x2*)(pb_ + (cbase ^ 16) + 2048); \
    l64x2 C2 = *(const l64x2*)(pb_ + (cbase ^ 16) + 4096); \
    l64x2 C3 = *(const l64x2*)(pb_ + (cbase ^ 16) + 6144); \
    __builtin_amdgcn_s_setprio(1); \
    QUAD(0, 4*(p)+2, C0[0], C1[0], C2[0], C3[0]) \
    QUAD(1, 4*(p)+2, C0[0], C1[0], C2[0], C3[0]) \
    QUAD(0, 4*(p)+3, C0[1], C1[1], C2[1], C3[1]) \
    QUAD(1, 4*(p)+3, C0[1], C1[1], C2[1], C3[1]) \
    __builtin_amdgcn_s_setprio(0); \
  } while (0)

#define G2K(pwb, X) do { \
    const u8* plb_ = (const u8*)pl; \
    bf16x8 paA = *(const bf16x8*)(plb_ + (pabase ^ (X))); \
    bf16x8 paB = *(const bf16x8*)(plb_ + (pabase ^ (X)) + 2048); \
    bf16x8 w0 = *(const bf16x8*)((pwb) + (wobase ^ (X))); \
    bf16x8 w1 = *(const bf16x8*)((pwb) + (wobase ^ (X)) + 2048); \
    bf16x8 w2 = *(const bf16x8*)((pwb) + (wobase ^ (X)) + 4096); \
    bf16x8 w3 = *(const bf16x8*)((pwb) + (wobase ^ (X)) + 6144); \
    bf16x8 w4 = *(const bf16x8*)((pwb) + (wobase ^ (X)) + 8192); \
    bf16x8 w5 = *(const bf16x8*)((pwb) + (wobase ^ (X)) + 10240); \
    bf16x8 w6 = *(const bf16x8*)((pwb) + (wobase ^ (X)) + 12288); \
    bf16x8 w7 = *(const bf16x8*)((pwb) + (wobase ^ (X)) + 14336); \
    __builtin_amdgcn_s_setprio(1); \
    oa[0][0] = MFBF(paA, w0, oa[0][0]); oa[0][1] = MFBF(paA, w1, oa[0][1]); \
    oa[0][2] = MFBF(paA, w2, oa[0][2]); oa[0][3] = MFBF(paA, w3, oa[0][3]); \
    oa[0][4] = MFBF(paA, w4, oa[0][4]); oa[0][5] = MFBF(paA, w5, oa[0][5]); \
    oa[0][6] = MFBF(paA, w6, oa[0][6]); oa[0][7] = MFBF(paA, w7, oa[0][7]); \
    oa[1][0] = MFBF(paB, w0, oa[1][0]); oa[1][1] = MFBF(paB, w1, oa[1][1]); \
    oa[1][2] = MFBF(paB, w2, oa[1][2]); oa[1][3] = MFBF(paB, w3, oa[1][3]); \
    oa[1][4] = MFBF(paB, w4, oa[1][4]); oa[1][5] = MFBF(paB, w5, oa[1][5]); \
    oa[1][6] = MFBF(paB, w6, oa[1][6]); oa[1][7] = MFBF(paB, w7, oa[1][7]); \
    __builtin_amdgcn_s_setprio(0); \
  } while (0)

#define TAIL(pwb, NCC) do { \
    _Pragma("unroll") \
    for (int ct = 0; ct < 4; ++ct) { \
      _Pragma("unroll") \
      for (int r = 0; r < 4; ++r) { \
        const int mA = mw * 32 + lg * 4 + r; \
        const int mB = mA + 16; \
        float vA = __builtin_amdgcn_exp2f(NB2 * (xq[0][r] + cq[ct] - 2.f * sacc[0][ct][r])); \
        float vB = __builtin_amdgcn_exp2f(NB2 * (xq[1][r] + cq[ct] - 2.f * sacc[1][ct][r])); \
        pl[mA * 64 + ((ct * 16 + l15) ^ ((mA & 7) << 3))] = f2bf(vA); \
        pl[mB * 64 + ((ct * 16 + l15) ^ ((mB & 7) << 3))] = f2bf(vB); \
      } \
      sacc[0][ct] = z4; sacc[1][ct] = z4; \
    } \
    asm volatile("s_waitcnt lgkmcnt(0)" ::: "memory"); \
    __builtin_amdgcn_sched_barrier(0); \
    G2K(pwb, 0); \
    G2K(pwb, 64); \
    _Pragma("unroll") \
    for (int ct = 0; ct < 4; ++ct) cq[ct] = csq_l[(NCC) * 64 + ct * 16 + l15]; \
  } while (0)

#pragma unroll 1
  for (int cc = 0; cc < 16; ++cc) {
    if (cc < 15) { S_CS(cc + 1); S_W(cc + 1); }
    const u8* csh = &cs[cc & 1][0];
    const u8* pwb = (const u8*)&wt[cc & 1][0];
    PHASE(csh, 0);
    PHASE(csh, 1);
    PHASE(csh, 2);
    PHASE(csh, 3);
    const int ncc = (cc < 15) ? cc + 1 : 15;
    TAIL(pwb, ncc);
    asm volatile("s_waitcnt vmcnt(0)" ::: "memory");
    __builtin_amdgcn_s_barrier();
    __builtin_amdgcn_sched_barrier(0);
  }

  // epilogue: out += partial (bias added by init_out)
#pragma unroll
  for (int rh = 0; rh < 2; ++rh)
#pragma unroll
    for (int ot = 0; ot < 8; ++ot) {
      const int o = ot * 16 + l15;
#pragma unroll
      for (int r = 0; r < 4; ++r) {
        const int m = mw * 32 + rh * 16 + lg * 4 + r;
        atomicAdd(&out[(r0 + m) * 128 + o], oa[rh][ot][r]);
      }
    }
#undef PHASE
#undef TAIL
#undef QUAD
#undef G2K
#undef S_CS
#undef S_W
}

extern "C" void kernel_launch(void* const* d_in, const int* in_sizes, int n_in,
                              void* d_out, int out_size, void* d_ws, size_t ws_size,
                              hipStream_t stream) {
  (void)in_sizes; (void)n_in; (void)out_size; (void)ws_size;
  const float* x   = (const float*)d_in[0];
  const float* cen = (const float*)d_in[1];
  const float* W   = (const float*)d_in[2];
  const float* b   = (const float*)d_in[3];
  u8* xq8 = (u8*)d_ws;                          // 16384*512 = 8 MB
  u8* cfr = xq8 + (size_t)16384 * 512;          // 4096*512  = 2 MB (frag stream)
  u16* wtg = (u16*)(cfr + (size_t)4096 * 512);  // 128*4096 bf16 = 1 MB
  float* csq = (float*)(wtg + 128 * 4096);      // 16 KB
  float* xsq = csq + 4096;                      // 64 KB
  prep_x8<<<2048, 512, 0, stream>>>(x, xq8, xsq);
  prep_cen<<<1024, 256, 0, stream>>>(cen, cfr, csq);
  prep_w<<<64, 256, 0, stream>>>(W, wtg);
  init_out<<<2048, 256, 0, stream>>>(b, (float*)d_out);
  rbf_main<<<256, 512, 0, stream>>>(xq8, cfr, wtg, csq, xsq, (float*)d_out);
}